// Round 3
// baseline (1775.221 us; speedup 1.0000x reference)
//
#include <hip/hip_runtime.h>

// CRF Viterbi forward decode — R2: wave-synchronous LDS broadcast, barrier-free,
// pipelined ds_reads, fmaxf value chain.
// potentials: [1024, 512, 48] f32, transition: [48, 48] f32.
// out = backpointers [1024, 511, 48] (as float values) ++ scores [1024, 48] f32.
//
// R0 post-mortem: per-read LDS waits serialized ~13 x 120cyc/step.
// R1 post-mortem: readlane broadcast -> 48+ live SGPRs -> allocator thrash, 5x VALU.
// R2: block = 1 wave (48 lanes, lane = dest tag j). State broadcast via single
// LDS buffer; wave-lockstep + in-order DS pipe means no s_barrier needed —
// only wave_barrier() (0-instruction scheduling fence) to pin write/read order.
// All 12 ds_read_b128 issued before any use -> progressive lgkmcnt waits.
// Value reduction via fmaxf (serial path ~28cyc); argmax indices off-path.

constexpr int B_ = 1024;
constexpr int T_ = 512;
constexpr int K_ = 48;
constexpr int C_ = 7;   // steps per chunk; 511 = 7 * 73, no remainder

__global__ __launch_bounds__(64, 1) void crf_viterbi_kernel(
    const float* __restrict__ pot,
    const float* __restrict__ trans,
    float* __restrict__ out)
{
    const int b = blockIdx.x;
    const int j = threadIdx.x;  // 0..47 = destination tag

    __shared__ float4 stv[K_ / 4];  // single state buffer (wave-synchronous)

    // Transition column j -> 48 VGPRs (reused 511 times).
    float tcol[K_];
    #pragma unroll
    for (int i = 0; i < K_; ++i) tcol[i] = trans[i * K_ + j];

    const float* pp = pot + (size_t)b * T_ * K_ + j;
    float* bpout    = out + (size_t)b * (T_ - 1) * K_ + j;
    float* scout    = out + (size_t)B_ * (T_ - 1) * K_ + (size_t)b * K_ + j;

    // t = 0 state.
    float myst = pp[0];
    ((float*)stv)[j] = myst;
    __builtin_amdgcn_wave_barrier();   // reads below must not hoist above write

    // Prefetch potentials one full chunk ahead (t = 1..7).
    float pbuf[C_];
    #pragma unroll
    for (int u = 0; u < C_; ++u) pbuf[u] = pp[(1 + u) * K_];

    for (int t0 = 1; t0 < T_; t0 += C_) {
        float pc[C_];
        #pragma unroll
        for (int u = 0; u < C_; ++u) pc[u] = pbuf[u];

        // Prefetch next chunk (last chunk: clamped dup loads, harmless).
        #pragma unroll
        for (int u = 0; u < C_; ++u) {
            int tn = t0 + C_ + u;
            if (tn > T_ - 1) tn = T_ - 1;
            pbuf[u] = pp[tn * K_];
        }

        #pragma unroll
        for (int u = 0; u < C_; ++u) {
            const int t = t0 + u;

            // (1) Issue ALL broadcast reads before any use (pipelined lgkmcnt).
            float4 sv[12];
            #pragma unroll
            for (int c = 0; c < 12; ++c) sv[c] = stv[c];
            __builtin_amdgcn_wave_barrier();  // write below must not hoist above reads

            // (2) 48 candidates: cand[i] = state[i] + trans[i][j].
            float cand[K_];
            #pragma unroll
            for (int c = 0; c < 12; ++c) {
                cand[4 * c + 0] = sv[c].x + tcol[4 * c + 0];
                cand[4 * c + 1] = sv[c].y + tcol[4 * c + 1];
                cand[4 * c + 2] = sv[c].z + tcol[4 * c + 2];
                cand[4 * c + 3] = sv[c].w + tcol[4 * c + 3];
            }

            // (3) Tournament: values via fmaxf (serial-path-critical), indices
            // via strict-'>' right-wins over ascending contiguous blocks
            // (= first-occurrence argmax, matching jnp).
            float m[24];
            int   x[24];
            #pragma unroll
            for (int p = 0; p < 24; ++p) {
                float a = cand[2 * p], c = cand[2 * p + 1];
                m[p] = fmaxf(a, c);
                x[p] = (c > a) ? (2 * p + 1) : (2 * p);
            }
            #pragma unroll
            for (int w = 12; w >= 3; w /= 2) {
                #pragma unroll
                for (int p = 0; p < w; ++p) {
                    float a = m[2 * p], c = m[2 * p + 1];
                    bool g = c > a;
                    m[p] = fmaxf(a, c);
                    x[p] = g ? x[2 * p + 1] : x[2 * p];
                }
            }
            // 3 blocks left: (0-15), (16-31), (32-47); left wins ties.
            float mm01 = fmaxf(m[0], m[1]);
            int   xx   = (m[1] > m[0]) ? x[1] : x[0];
            bool  g2   = m[2] > mm01;
            float mm   = fmaxf(mm01, m[2]);
            xx         = g2 ? x[2] : xx;

            // (4) New state: write LDS ASAP (feeds next step's reads).
            myst = pc[u] + mm;
            ((float*)stv)[j] = myst;
            __builtin_amdgcn_wave_barrier();  // next reads must not hoist above write

            // (5) Off-path: backpointer store.
            bpout[(size_t)(t - 1) * K_] = (float)xx;
        }
    }

    // Final Viterbi scores.
    *scout = myst;
}

extern "C" void kernel_launch(void* const* d_in, const int* in_sizes, int n_in,
                              void* d_out, int out_size, void* d_ws, size_t ws_size,
                              hipStream_t stream) {
    const float* pot   = (const float*)d_in[0];
    const float* trans = (const float*)d_in[1];
    float* out         = (float*)d_out;
    crf_viterbi_kernel<<<dim3(B_), dim3(K_), 0, stream>>>(pot, trans, out);
}

// Round 4
// 322.874 us; speedup vs baseline: 5.4982x; 5.4982x over previous
//
#include <hip/hip_runtime.h>

// CRF Viterbi forward decode — R3: value/index decoupling, index-shadow pipelining.
// potentials: [1024, 512, 48] f32, transition: [48, 48] f32.
// out = backpointers [1024, 511, 48] (as float values) ++ scores [1024, 48] f32.
//
// Block = 1 wave, 48 lanes, lane j = destination tag; 1 block per batch.
// Per step t: issue 12 ds_read_b128 (static offsets, pipelined) -> while they
// fly, run step t-1's index extraction (equality scan vs saved exact max =
// first-occurrence argmax, numpy-identical) + bp store -> then 48 adds,
// 47-fmaxf value tree, myst, ds_write, wave_barrier.
// No __syncthreads (single-wave workgroup; in-order DS pipe — validated R2).
// No index tournament arrays (R1/R2 post-mortem: big live arrays + predicate
// pairs -> 5x VALU inflation). Serial cndmask chain uses inline consts 0..47.

constexpr int B_ = 1024;
constexpr int T_ = 512;
constexpr int K_ = 48;
constexpr int C_ = 6;   // chunk; steps t=2..511 -> 510 = 6 * 85, no remainder

__global__ __launch_bounds__(64, 1) void crf_viterbi_kernel(
    const float* __restrict__ pot,
    const float* __restrict__ trans,
    float* __restrict__ out)
{
    const int b = blockIdx.x;
    const int j = threadIdx.x;  // 0..47 = destination tag

    __shared__ __align__(16) float stv[K_];  // single wave-synchronous state buffer

    // Transition column j -> 48 VGPRs (reused 511 times).
    float tcol[K_];
    #pragma unroll
    for (int i = 0; i < K_; ++i) tcol[i] = trans[i * K_ + j];

    const float* pp = pot + (size_t)b * T_ * K_ + j;
    float* bpp      = out + (size_t)b * (T_ - 1) * K_ + j;          // walking bp ptr
    float* scout    = out + (size_t)B_ * (T_ - 1) * K_ + (size_t)b * K_ + j;

    // t = 0 state.
    float myst = pp[0];
    stv[j] = myst;
    __builtin_amdgcn_wave_barrier();

    // Shadow state: candidates + exact max of previous step (for deferred argmax).
    float cand_prev[K_];
    float mm_prev = 0.0f;

    // One step. do_shadow is always a compile-time literal at call sites.
    auto step = [&](float pcur, bool do_shadow) {
        // (1) Batched broadcast reads — 12 x ds_read_b128, static offsets.
        float4 sv[12];
        const float4* stv4 = (const float4*)stv;
        #pragma unroll
        for (int c = 0; c < 12; ++c) sv[c] = stv4[c];

        // (2) Shadow: previous step's argmax + bp store (fills read latency).
        if (do_shadow) {
            int xx = K_ - 1;
            #pragma unroll
            for (int i = K_ - 2; i >= 0; --i)
                xx = (cand_prev[i] == mm_prev) ? i : xx;   // first-occurrence
            *bpp = (float)xx;
            bpp += K_;
        }

        // (3) 48 candidates (overwrite shadow buffer — old values consumed above).
        #pragma unroll
        for (int c = 0; c < 12; ++c) {
            cand_prev[4 * c + 0] = sv[c].x + tcol[4 * c + 0];
            cand_prev[4 * c + 1] = sv[c].y + tcol[4 * c + 1];
            cand_prev[4 * c + 2] = sv[c].z + tcol[4 * c + 2];
            cand_prev[4 * c + 3] = sv[c].w + tcol[4 * c + 3];
        }

        // (4) Value-only max tree (47 fmaxf; fmax returns one operand bitwise,
        // so equality extraction above is exact).
        float m[24];
        #pragma unroll
        for (int p = 0; p < 24; ++p) m[p] = fmaxf(cand_prev[2 * p], cand_prev[2 * p + 1]);
        #pragma unroll
        for (int p = 0; p < 12; ++p) m[p] = fmaxf(m[2 * p], m[2 * p + 1]);
        #pragma unroll
        for (int p = 0; p < 6; ++p)  m[p] = fmaxf(m[2 * p], m[2 * p + 1]);
        #pragma unroll
        for (int p = 0; p < 3; ++p)  m[p] = fmaxf(m[2 * p], m[2 * p + 1]);
        float mm = fmaxf(fmaxf(m[0], m[1]), m[2]);
        mm_prev = mm;

        // (5) New state -> LDS; fence orders write(t) before reads(t+1).
        myst = pcur + mm;
        stv[j] = myst;
        __builtin_amdgcn_wave_barrier();
    };

    // Potential for t=1 and prefetch t=2..7.
    float p1 = pp[(size_t)1 * K_];
    float pbuf[C_];
    #pragma unroll
    for (int u = 0; u < C_; ++u) pbuf[u] = pp[(size_t)(2 + u) * K_];

    // t = 1: no shadow yet.
    step(p1, false);

    for (int t0 = 2; t0 < T_; t0 += C_) {   // t0 = 2, 8, ..., 506 (85 chunks)
        float pc[C_];
        #pragma unroll
        for (int u = 0; u < C_; ++u) pc[u] = pbuf[u];

        // Prefetch next chunk (clamped; dup loads harmless).
        #pragma unroll
        for (int u = 0; u < C_; ++u) {
            int tn = t0 + C_ + u;
            if (tn > T_ - 1) tn = T_ - 1;
            pbuf[u] = pp[(size_t)tn * K_];
        }

        #pragma unroll
        for (int u = 0; u < C_; ++u) step(pc[u], true);
    }

    // Final shadow: argmax for t = 511.
    {
        int xx = K_ - 1;
        #pragma unroll
        for (int i = K_ - 2; i >= 0; --i)
            xx = (cand_prev[i] == mm_prev) ? i : xx;
        *bpp = (float)xx;
    }

    // Final Viterbi scores.
    *scout = myst;
}

extern "C" void kernel_launch(void* const* d_in, const int* in_sizes, int n_in,
                              void* d_out, int out_size, void* d_ws, size_t ws_size,
                              hipStream_t stream) {
    const float* pot   = (const float*)d_in[0];
    const float* trans = (const float*)d_in[1];
    float* out         = (float*)d_out;
    crf_viterbi_kernel<<<dim3(B_), dim3(K_), 0, stream>>>(pot, trans, out);
}

// Round 5
// 313.192 us; speedup vs baseline: 5.6682x; 1.0309x over previous
//
#include <hip/hip_runtime.h>

// CRF Viterbi forward decode — R4: R3 skeleton + parity-double-buffered cand
// (kills per-step v_mov copy loop) + v_max3 ternary value tree (47 -> 24 ops).
// potentials: [1024, 512, 48] f32, transition: [48, 48] f32.
// out = backpointers [1024, 511, 48] (as float values) ++ scores [1024, 48] f32.
//
// Block = 1 wave, 48 lanes, lane j = destination tag; 1 block per batch.
// Per step t: 12 ds_read_b128 batched (pipelined lgkmcnt) -> shadow = step
// t-1's argmax (equality scan vs exact max = first-occurrence, numpy-identical)
// + bp store, filling the LDS latency window -> 48 adds -> max3 tree -> myst
// -> ds_write -> wave_barrier. No __syncthreads (single-wave workgroup,
// in-order DS pipe — validated R2/R3, absmax 0).
// R3 post-mortem: ~300 cyc/step slop = loop-carried cand copy (~48 v_mov) +
// unfused binary fmax tree. R4 removes both; nothing else touched.

constexpr int B_ = 1024;
constexpr int T_ = 512;
constexpr int K_ = 48;
constexpr int C_ = 6;   // steps t=2..511 -> 510 = 6 * 85, no remainder

__global__ __launch_bounds__(64, 1) void crf_viterbi_kernel(
    const float* __restrict__ pot,
    const float* __restrict__ trans,
    float* __restrict__ out)
{
    const int b = blockIdx.x;
    const int j = threadIdx.x;  // 0..47 = destination tag

    __shared__ __align__(16) float stv[K_];  // single wave-synchronous state buffer

    // Transition column j -> 48 VGPRs (reused 511 times).
    float tcol[K_];
    #pragma unroll
    for (int i = 0; i < K_; ++i) tcol[i] = trans[i * K_ + j];

    const float* pp = pot + (size_t)b * T_ * K_ + j;
    float* bpp      = out + (size_t)b * (T_ - 1) * K_ + j;          // walking bp ptr
    float* scout    = out + (size_t)B_ * (T_ - 1) * K_ + (size_t)b * K_ + j;

    // t = 0 state.
    float myst = pp[0];
    stv[j] = myst;
    __builtin_amdgcn_wave_barrier();

    // Parity-double-buffered candidates + exact max (shadow reads the buffer
    // the PREVIOUS step wrote; no register copies).
    float candA[K_], candB[K_];
    float mmA = 0.0f, mmB = 0.0f;

// One step. CN/MMN: written this step; CO/MMO: previous step's (shadow input).
// DOSH is a compile-time literal at every expansion.
#define STEP(PCUR, CN, CO, MMN, MMO, DOSH)                                     \
    do {                                                                       \
        /* (1) Batched broadcast reads — 12 x ds_read_b128, static offsets. */ \
        float4 sv[12];                                                         \
        const float4* stv4 = (const float4*)stv;                               \
        _Pragma("unroll")                                                      \
        for (int c = 0; c < 12; ++c) sv[c] = stv4[c];                          \
        /* (2) Shadow: previous step's argmax + bp store (fills LDS window) */ \
        if (DOSH) {                                                            \
            int xx = K_ - 1;                                                   \
            _Pragma("unroll")                                                  \
            for (int i = K_ - 2; i >= 0; --i)                                  \
                xx = (CO[i] == MMO) ? i : xx;   /* first-occurrence */         \
            *bpp = (float)xx;                                                  \
            bpp += K_;                                                         \
        }                                                                      \
        /* (3) 48 candidates into the fresh buffer (old one now dead). */      \
        _Pragma("unroll")                                                      \
        for (int c = 0; c < 12; ++c) {                                         \
            CN[4 * c + 0] = sv[c].x + tcol[4 * c + 0];                         \
            CN[4 * c + 1] = sv[c].y + tcol[4 * c + 1];                         \
            CN[4 * c + 2] = sv[c].z + tcol[4 * c + 2];                         \
            CN[4 * c + 3] = sv[c].w + tcol[4 * c + 3];                         \
        }                                                                      \
        /* (4) Ternary value tree -> v_max3_f32: 16+5+2+1 = 24 ops, depth 4.*/ \
        float m1[16];                                                          \
        _Pragma("unroll")                                                      \
        for (int k = 0; k < 16; ++k)                                           \
            m1[k] = fmaxf(fmaxf(CN[3 * k], CN[3 * k + 1]), CN[3 * k + 2]);     \
        float m2[6];                                                           \
        _Pragma("unroll")                                                      \
        for (int k = 0; k < 5; ++k)                                            \
            m2[k] = fmaxf(fmaxf(m1[3 * k], m1[3 * k + 1]), m1[3 * k + 2]);     \
        m2[5] = m1[15];                                                        \
        float m30 = fmaxf(fmaxf(m2[0], m2[1]), m2[2]);                         \
        float m31 = fmaxf(fmaxf(m2[3], m2[4]), m2[5]);                         \
        float mm  = fmaxf(m30, m31);                                           \
        MMN = mm;                                                              \
        /* (5) New state -> LDS; fence orders write(t) before reads(t+1). */   \
        myst = (PCUR) + mm;                                                    \
        stv[j] = myst;                                                         \
        __builtin_amdgcn_wave_barrier();                                       \
    } while (0)

    // Potential for t=1 and prefetch t=2..7.
    float p1 = pp[(size_t)1 * K_];
    float pbuf[C_];
    #pragma unroll
    for (int u = 0; u < C_; ++u) pbuf[u] = pp[(size_t)(2 + u) * K_];

    // t = 1 (odd): writes candB; no shadow yet.
    STEP(p1, candB, candA, mmB, mmA, false);

    for (int t0 = 2; t0 < T_; t0 += C_) {   // t0 = 2, 8, ..., 506 (85 chunks)
        float pc[C_];
        #pragma unroll
        for (int u = 0; u < C_; ++u) pc[u] = pbuf[u];

        // Prefetch next chunk (clamped; dup loads harmless).
        #pragma unroll
        for (int u = 0; u < C_; ++u) {
            int tn = t0 + C_ + u;
            if (tn > T_ - 1) tn = T_ - 1;
            pbuf[u] = pp[(size_t)tn * K_];
        }

        // t = t0 + u; even t writes A / reads B, odd t writes B / reads A.
        STEP(pc[0], candA, candB, mmA, mmB, true);
        STEP(pc[1], candB, candA, mmB, mmA, true);
        STEP(pc[2], candA, candB, mmA, mmB, true);
        STEP(pc[3], candB, candA, mmB, mmA, true);
        STEP(pc[4], candA, candB, mmA, mmB, true);
        STEP(pc[5], candB, candA, mmB, mmA, true);
    }

    // Final shadow: argmax for t = 511 (odd -> candB/mmB).
    {
        int xx = K_ - 1;
        #pragma unroll
        for (int i = K_ - 2; i >= 0; --i)
            xx = (candB[i] == mmB) ? i : xx;
        *bpp = (float)xx;
    }

    // Final Viterbi scores.
    *scout = myst;
#undef STEP
}

extern "C" void kernel_launch(void* const* d_in, const int* in_sizes, int n_in,
                              void* d_out, int out_size, void* d_ws, size_t ws_size,
                              hipStream_t stream) {
    const float* pot   = (const float*)d_in[0];
    const float* trans = (const float*)d_in[1];
    float* out         = (float*)d_out;
    crf_viterbi_kernel<<<dim3(B_), dim3(K_), 0, stream>>>(pot, trans, out);
}